// Round 9
// baseline (216.205 us; speedup 1.0000x reference)
//
#include <hip/hip_runtime.h>
#include <hip/hip_bf16.h>
#include <math.h>

// CodecAttention: x->QKV proj (bf16 MFMA, V written tiled-transposed) ->
// RMSNorm(q,k) -> MFMA sliding-window ALiBi attention (win=16) -> out proj.
// B=4 T=2048 DIM=1024 H=8 D=128.

#define TSEQ 2048
#define DIMW 1024
#define NHEAD 8
#define WIN 16

typedef __bf16 bf16x8_t __attribute__((ext_vector_type(8)));
typedef float f32x4_t __attribute__((ext_vector_type(4)));

__device__ __forceinline__ unsigned short f2bf(float f) {
  unsigned u = __float_as_uint(f);
  u += 0x7fffu + ((u >> 16) & 1u);   // round-to-nearest-even
  return (unsigned short)(u >> 16);
}
__device__ __forceinline__ float bflo(unsigned u) { return __uint_as_float(u << 16); }
__device__ __forceinline__ float bfhi(unsigned u) { return __uint_as_float(u & 0xffff0000u); }

// ---------- f32 -> bf16 conversion of x ----------
__global__ __launch_bounds__(256)
void k_conv_x(const float* __restrict__ x, unsigned short* __restrict__ xb, int n4) {
  int i = blockIdx.x * 256 + threadIdx.x;
  if (i >= n4) return;
  float4 v = ((const float4*)x)[i];
  ushort4 o;
  o.x = f2bf(v.x); o.y = f2bf(v.y); o.z = f2bf(v.z); o.w = f2bf(v.w);
  ((ushort4*)xb)[i] = o;
}

// ---------- transpose + convert weights: Wt[z][n][k] = w_z[k][n] ----------
__global__ __launch_bounds__(256)
void k_conv_w(const float* __restrict__ wq, const float* __restrict__ wk,
              const float* __restrict__ wv, const float* __restrict__ wo,
              unsigned short* __restrict__ Wt) {
  __shared__ float tile[32][33];
  const int z = blockIdx.z;
  const float* src = (z == 0) ? wq : (z == 1) ? wk : (z == 2) ? wv : wo;
  const int n0 = blockIdx.x * 32;
  const int k0 = blockIdx.y * 32;
  const int tx = threadIdx.x, ty = threadIdx.y;  // 32 x 8
#pragma unroll
  for (int i = 0; i < 4; ++i)
    tile[ty + 8 * i][tx] = src[(size_t)(k0 + ty + 8 * i) * DIMW + n0 + tx];
  __syncthreads();
#pragma unroll
  for (int i = 0; i < 4; ++i)
    Wt[(size_t)z * DIMW * DIMW + (size_t)(n0 + ty + 8 * i) * DIMW + k0 + tx] =
        f2bf(tile[tx][ty + 8 * i]);
}

// ---------- bf16 TN GEMM: 128x128 tile, ring-3, 3 blocks/CU ----------
// K-loop identical to R7 (verified: SQ_LDS_BANK_CONFLICT==0, 3 blocks/CU).
// LDS-transpose epilogue for MODE 0 (R9: aliasing-safe): bf16 C-stores
// previously wrote 32B (Cb) / 16B (Vt) segments -> L2 write-allocate RMW
// (~55MB of the 125MB FETCH). Each wave stages its 64x64 tile in a private
// [64][72] ushort LDS buffer (rows 144B = 16B-aligned) and stores full-line
// runs: Cb as 128B-per-row uint4 runs; Vt (stored transposed in LDS) as 1KB
// contiguous Vt2 t-chunks. Read-back uses __builtin_memcpy (byte semantics:
// ordered after the ushort stores -- R8's *(unsigned*) punning was strict-
// aliasing UB and the compiler hoisted reads above writes -> NaN).
#define GLDS(gp, lp)                                                        \
  __builtin_amdgcn_global_load_lds(                                         \
      (const __attribute__((address_space(1))) void*)(gp),                  \
      (__attribute__((address_space(3))) void*)(lp), 16, 0, 0)

template <int MODE>
__global__ __launch_bounds__(256, 3)
void k_gemm(const unsigned short* __restrict__ A,   // [M][K] bf16
            const unsigned short* __restrict__ Bt,  // [N][K] bf16
            unsigned short* __restrict__ Cb,        // bf16 out (MODE 0, q|k part)
            unsigned short* __restrict__ Vt,        // bf16 out (MODE 0, v part, tiled)
            float* __restrict__ Cf,                 // f32 out  (MODE 1)
            int M, int N, int K) {
  __shared__ __align__(16) unsigned char smem[49152];  // 3 x (A 8KB + B 8KB)
  const int tid = threadIdx.x;
  const int lane = tid & 63;
  const int w = tid >> 6;             // wave 0..3
  const int wm = w >> 1, wn = w & 1;  // 2 x 2

  // XCD-aware bijective swizzle (grids are multiples of 8)
  const int nwg = gridDim.x * gridDim.y;
  int flat = blockIdx.y * gridDim.x + blockIdx.x;
  flat = (flat & 7) * (nwg >> 3) + (flat >> 3);
  const int bx = flat % gridDim.x;
  const int by = flat / gridDim.x;

  // staging: per slice per thread 2 A + 2 B loads (16B each); source
  // col-group pre-swizzled: cg = (lane&3) ^ ((lane>>3)&3).
  const int r2 = lane >> 2;
  const int cg = ((lane & 3) ^ ((lane >> 3) & 3)) * 8;  // elements

#define IA(sl_, ks_, h_)                                                       \
  GLDS(A + (size_t)(by * 128 + (h_)*64 + w * 16 + r2) * K + (ks_)*32 + cg,     \
       smem + (sl_)*16384 + ((h_)*64 + w * 16) * 64)
#define IB(sl_, ks_, h_)                                                       \
  GLDS(Bt + (size_t)(bx * 128 + (h_)*64 + w * 16 + r2) * K + (ks_)*32 + cg,    \
       smem + (sl_)*16384 + 8192 + ((h_)*64 + w * 16) * 64)
#define STAGE(ks_)                                                             \
  do {                                                                         \
    const int sl_ = (ks_) % 3;                                                 \
    IA(sl_, (ks_), 0); IB(sl_, (ks_), 0);                                      \
    IA(sl_, (ks_), 1); IB(sl_, (ks_), 1);                                      \
  } while (0)

  // frag reads: slot g = (lane>>4) ^ ((lane>>1)&3)
  const int swz = ((lane >> 4) ^ ((lane >> 1) & 3)) * 16;
  const int aRd = (wm * 64 + (lane & 15)) * 64 + swz;
  const int bRd = 8192 + (wn * 64 + (lane & 15)) * 64 + swz;

  f32x4_t acc[4][4];
#pragma unroll
  for (int m = 0; m < 4; ++m)
#pragma unroll
    for (int n = 0; n < 4; ++n) acc[m][n] = (f32x4_t){0.f, 0.f, 0.f, 0.f};

  const int NS = K >> 5;  // 32 slices
  STAGE(0); STAGE(1);     // distance 2: 8 loads in flight
#pragma unroll 1
  for (int s = 0; s < NS; ++s) {
    if (s + 1 < NS) asm volatile("s_waitcnt vmcnt(4)" ::: "memory");
    else            asm volatile("s_waitcnt vmcnt(0)" ::: "memory");
    asm volatile("s_barrier" ::: "memory");
    if (s + 2 < NS) STAGE(s + 2);
    const unsigned char* sp = smem + (s % 3) * 16384;
    bf16x8_t af[4], bfr[4];
#pragma unroll
    for (int n = 0; n < 4; ++n) bfr[n] = *(const bf16x8_t*)(sp + bRd + n * 1024);
#pragma unroll
    for (int m = 0; m < 4; ++m) af[m] = *(const bf16x8_t*)(sp + aRd + m * 1024);
    __builtin_amdgcn_s_setprio(1);
#pragma unroll
    for (int m = 0; m < 4; ++m)
#pragma unroll
      for (int n = 0; n < 4; ++n)
        acc[m][n] = __builtin_amdgcn_mfma_f32_16x16x32_bf16(af[m], bfr[n], acc[m][n], 0, 0, 0);
    __builtin_amdgcn_s_setprio(0);
  }

  // ---- epilogue ----
  const int g = lane >> 4, c = lane & 15;
  if (MODE == 1) {
    // f32 out: 64B full-line runs already
    const int row0 = by * 128 + wm * 64 + (g << 2);
    const int col0 = bx * 128 + wn * 64 + c;
#pragma unroll
    for (int m = 0; m < 4; ++m)
#pragma unroll
      for (int n = 0; n < 4; ++n)
#pragma unroll
        for (int r = 0; r < 4; ++r)
          Cf[(size_t)(row0 + m * 16 + r) * N + col0 + n * 16] = acc[m][n][r];
  } else {
    __syncthreads();  // staging reads done; smem reusable
    unsigned short* wbuf = (unsigned short*)(smem + w * 9216);  // [64][72]
    const bool isV = (bx * 128 >= 2048);
#pragma unroll
    for (int m = 0; m < 4; ++m)
#pragma unroll
      for (int n = 0; n < 4; ++n)
#pragma unroll
        for (int r = 0; r < 4; ++r) {
          const int rl = m * 16 + (g << 2) + r;  // row (t) local 0..63
          const int cl = n * 16 + c;             // col (d) local 0..63
          const unsigned short v = f2bf(acc[m][n][r]);
          if (isV) wbuf[cl * 72 + rl] = v;       // store transposed for Vt
          else     wbuf[rl * 72 + cl] = v;
        }
    // wave-private buffer; memcpy readback is byte-typed => ordered after
    // the ushort stores (no strict-aliasing reordering).
    if (!isV) {
      const int grow = by * 128 + wm * 64;
      const int gcol = bx * 128 + wn * 64;
#pragma unroll
      for (int rr = 0; rr < 8; ++rr) {
        const int row = rr * 8 + (lane >> 3);
        const int seg = lane & 7;
        uint4 u;
        __builtin_memcpy(&u, wbuf + row * 72 + seg * 8, 16);
        *(uint4*)(Cb + (size_t)(grow + row) * 2048 + gcol + seg * 8) = u;
      }
    } else {
      const int tt0 = (by * 128 + wm * 64) & 2047;
      const int bb = (by * 128) >> 11;
      const int hh = bx - 16;
      const int dd0 = wn * 64;
      unsigned short* vdst =
          Vt + ((((size_t)(bb * NHEAD + hh)) * 256 + (tt0 >> 3)) * 128 + dd0 + lane) * 8;
#pragma unroll
      for (int tc = 0; tc < 8; ++tc) {
        uint4 u;
        __builtin_memcpy(&u, wbuf + lane * 72 + tc * 8, 16);
        *(uint4*)(vdst + (size_t)tc * 1024) = u;  // 1KB-contig t-chunk runs
      }
    }
  }
#undef IA
#undef IB
#undef STAGE
}

// ---------- in-place RMSNorm on q (cols 0..1023) and k (cols 1024..2047) ----------
__global__ __launch_bounds__(256)
void k_rmsnorm(unsigned short* __restrict__ qk, const float* __restrict__ qw,
               const float* __restrict__ kw) {
  const int row = blockIdx.x;
  const int tid = threadIdx.x;
  unsigned short* base = qk + (size_t)row * 2048;
  uint2 uq = *(const uint2*)(base + tid * 4);
  uint2 uk = *(const uint2*)(base + 1024 + tid * 4);
  float q0 = bflo(uq.x), q1 = bfhi(uq.x), q2 = bflo(uq.y), q3 = bfhi(uq.y);
  float k0 = bflo(uk.x), k1 = bfhi(uk.x), k2 = bflo(uk.y), k3 = bfhi(uk.y);
  float sq = q0 * q0 + q1 * q1 + q2 * q2 + q3 * q3;
  float sk = k0 * k0 + k1 * k1 + k2 * k2 + k3 * k3;
#pragma unroll
  for (int off = 32; off > 0; off >>= 1) {
    sq += __shfl_xor(sq, off);
    sk += __shfl_xor(sk, off);
  }
  __shared__ float red[8];
  const int w = tid >> 6;
  if ((tid & 63) == 0) { red[w] = sq; red[4 + w] = sk; }
  __syncthreads();
  sq = red[0] + red[1] + red[2] + red[3];
  sk = red[4] + red[5] + red[6] + red[7];
  const float rq = rsqrtf(sq * (1.0f / 1024.0f) + 1e-6f);
  const float rk = rsqrtf(sk * (1.0f / 1024.0f) + 1e-6f);
  const int c = tid * 4;
  uint2 oq, ok;
  oq.x = (unsigned)f2bf(q0 * rq * qw[c]) | ((unsigned)f2bf(q1 * rq * qw[c + 1]) << 16);
  oq.y = (unsigned)f2bf(q2 * rq * qw[c + 2]) | ((unsigned)f2bf(q3 * rq * qw[c + 3]) << 16);
  ok.x = (unsigned)f2bf(k0 * rk * kw[c]) | ((unsigned)f2bf(k1 * rk * kw[c + 1]) << 16);
  ok.y = (unsigned)f2bf(k2 * rk * kw[c + 2]) | ((unsigned)f2bf(k3 * rk * kw[c + 3]) << 16);
  *(uint2*)(base + tid * 4) = oq;
  *(uint2*)(base + 1024 + tid * 4) = ok;
}

// ---------- MFMA sliding-window ALiBi attention ----------
// One wave per 16 queries of one (b,h). Key window: 32 keys [t0-16, t0+16).
// Swapped QK^T (A=K, B=Q) -> S^T. All global loads (Q, K, all 8 V-frags)
// issued BEFORE the QK^T MFMAs (T14). V read from tiled Vt2[bh][t>>3][d][t&7]
// (coalesced). Output staged per-wave in LDS [16][136] (16B rows) and stored
// as 64B-coalesced uint4 runs; readback via __builtin_memcpy (aliasing-safe).
__global__ __launch_bounds__(256)
void k_attn(const unsigned short* __restrict__ qk,   // [8192][2048] q|k (normalized)
            const unsigned short* __restrict__ vt,   // Vt2 tiled
            unsigned short* __restrict__ outb) {     // [8192][1024] bf16
  __shared__ __align__(16) unsigned char plds_all[4][1280];      // P: 16 x 80B
  __shared__ __align__(16) unsigned short obuf_all[4][16 * 136]; // out: 16 x 136
  const int lane = threadIdx.x & 63;
  const int wv = threadIdx.x >> 6;
  unsigned char* plds = plds_all[wv];
  unsigned short* obuf = obuf_all[wv];
  const int bh = blockIdx.y;                 // 0..31
  const int b = bh >> 3, h = bh & 7;
  const int t0 = blockIdx.x * 64 + wv * 16;
  const int g = lane >> 4, c = lane & 15;
  const int jlo = t0 - 16;

  // ---- issue ALL global loads first ----
  const unsigned short* qrow = qk + (size_t)(b * TSEQ + t0 + c) * 2048 + h * 128 + g * 8;
  bf16x8_t qf[4];
#pragma unroll
  for (int kc = 0; kc < 4; ++kc) qf[kc] = *(const bf16x8_t*)(qrow + kc * 32);

  const int j0 = jlo + c;
  const int j0c = (j0 < 0) ? 0 : j0;
  const unsigned short* krow0 = qk + (size_t)(b * TSEQ + j0c) * 2048 + 1024 + h * 128 + g * 8;
  const unsigned short* krow1 = qk + (size_t)(b * TSEQ + t0 + c) * 2048 + 1024 + h * 128 + g * 8;
  bf16x8_t kf0[4], kf1[4];
#pragma unroll
  for (int kc = 0; kc < 4; ++kc) {
    kf0[kc] = *(const bf16x8_t*)(krow0 + kc * 32);
    kf1[kc] = *(const bf16x8_t*)(krow1 + kc * 32);
  }

  int tc = (jlo >> 3) + g;
  if (tc < 0) tc = 0;               // masked rows: zero P weight
  const unsigned short* vbase = vt + (((size_t)bh * 256 + tc) * 128 + c) * 8;
  bf16x8_t vf[8];
#pragma unroll
  for (int n = 0; n < 8; ++n) vf[n] = *(const bf16x8_t*)(vbase + n * 128);

  // ---- QK^T ----
  f32x4_t s0 = (f32x4_t){0.f, 0.f, 0.f, 0.f};
  f32x4_t s1 = (f32x4_t){0.f, 0.f, 0.f, 0.f};
#pragma unroll
  for (int kc = 0; kc < 4; ++kc) {
    s0 = __builtin_amdgcn_mfma_f32_16x16x32_bf16(kf0[kc], qf[kc], s0, 0, 0, 0);
    s1 = __builtin_amdgcn_mfma_f32_16x16x32_bf16(kf1[kc], qf[kc], s1, 0, 0, 0);
  }

  // scores + mask + bias. key kk = z*16 + g*4 + r; query = c; rel = kk-16-c.
  const float scale = 0.08838834764831845f;  // 1/sqrt(128)
  const float slope = 1.0f / (float)(1 << h);
  float val[8];
#pragma unroll
  for (int z = 0; z < 2; ++z)
#pragma unroll
    for (int r = 0; r < 4; ++r) {
      const int kk = z * 16 + g * 4 + r;
      const int rel = kk - 16 - c;
      const bool ok = (rel <= 0) & (rel >= -WIN) & (jlo + kk >= 0);
      const float sc = (z == 0) ? s0[r] : s1[r];
      val[z * 4 + r] = ok ? (sc * scale + slope * (float)rel) : -1.0e30f;
    }
  float m = val[0];
#pragma unroll
  for (int i = 1; i < 8; ++i) m = fmaxf(m, val[i]);
  m = fmaxf(m, __shfl_xor(m, 16));
  m = fmaxf(m, __shfl_xor(m, 32));
  float e[8], s = 0.f;
#pragma unroll
  for (int i = 0; i < 8; ++i) { e[i] = __expf(val[i] - m); s += e[i]; }
  s += __shfl_xor(s, 16);
  s += __shfl_xor(s, 32);
  const float inv = 1.0f / s;

  // P -> LDS [query c][key kk], row stride 80B: 2-way banks = free
#pragma unroll
  for (int z = 0; z < 2; ++z) {
    uint2 pk;
    pk.x = (unsigned)f2bf(e[z * 4 + 0] * inv) | ((unsigned)f2bf(e[z * 4 + 1] * inv) << 16);
    pk.y = (unsigned)f2bf(e[z * 4 + 2] * inv) | ((unsigned)f2bf(e[z * 4 + 3] * inv) << 16);
    *(uint2*)(plds + c * 80 + z * 32 + g * 8) = pk;
  }
  const bf16x8_t pf = *(const bf16x8_t*)(plds + c * 80 + g * 16);

  // ---- PV -> LDS out-tile ----
#pragma unroll
  for (int n = 0; n < 8; ++n) {
    f32x4_t o = __builtin_amdgcn_mfma_f32_16x16x32_bf16(pf, vf[n], (f32x4_t){0.f, 0.f, 0.f, 0.f},
                                                        0, 0, 0);
#pragma unroll
    for (int r = 0; r < 4; ++r)
      obuf[(g * 4 + r) * 136 + n * 16 + c] = f2bf(o[r]);
  }

  // ---- coalesced store: 4 uint4 per lane, 64B runs ----
  unsigned short* obase = outb + (size_t)(b * TSEQ + t0) * 1024 + h * 128;
  const int q = lane >> 2, s4 = lane & 3;
#pragma unroll
  for (int i = 0; i < 4; ++i) {
    const int seg = i * 4 + s4;
    uint4 u;
    __builtin_memcpy(&u, obuf + q * 136 + seg * 8, 16);
    *(uint4*)(obase + (size_t)q * 1024 + seg * 8) = u;
  }
}

extern "C" void kernel_launch(void* const* d_in, const int* in_sizes, int n_in,
                              void* d_out, int out_size, void* d_ws, size_t ws_size,
                              hipStream_t stream) {
  const float* x = (const float*)d_in[0];
  const float* wq = (const float*)d_in[1];
  const float* wk = (const float*)d_in[2];
  const float* wv = (const float*)d_in[3];
  const float* wo = (const float*)d_in[4];
  const float* qnw = (const float*)d_in[5];
  const float* knw = (const float*)d_in[6];
  float* out = (float*)d_out;

  const int M = 4 * TSEQ;  // 8192 rows
  // workspace (75.5 MB):
  //   xb  [M][1024] bf16 (16.8 MB)  -- x bf16; later reused as attention output
  //   Wt  [4][1024][1024] bf16 (8.4 MB)
  //   qk  [M][2048] bf16 (33.5 MB)  -- q|k (normalized in place)
  //   Vt2 [32][256][128][8] bf16 (16.8 MB) -- V tiled-transposed per (b,h)
  unsigned short* xb = (unsigned short*)d_ws;
  unsigned short* Wt = xb + (size_t)M * DIMW;
  unsigned short* qkb = Wt + (size_t)4 * DIMW * DIMW;
  unsigned short* Vt = qkb + (size_t)M * 2048;
  if (ws_size < ((size_t)M * DIMW + (size_t)4 * DIMW * DIMW + (size_t)M * 2048 +
                 (size_t)M * 2048) * 2) return;

  k_conv_x<<<(M * DIMW / 4 + 255) / 256, 256, 0, stream>>>(x, xb, M * DIMW / 4);
  k_conv_w<<<dim3(32, 32, 4), dim3(32, 8), 0, stream>>>(wq, wk, wv, wo, Wt);
  k_gemm<0><<<dim3(24, 64), 256, 0, stream>>>(xb, Wt, qkb, Vt, nullptr, M, 3072, 1024);
  k_rmsnorm<<<M, 256, 0, stream>>>(qkb, qnw, knw);
  k_attn<<<dim3(TSEQ / 64, 32), 256, 0, stream>>>(qkb, Vt, xb);  // xb = attn out
  k_gemm<1><<<dim3(8, 64), 256, 0, stream>>>(xb, Wt + (size_t)3 * DIMW * DIMW, nullptr,
                                             nullptr, out, M, 1024, 1024);
}

// Round 10
// 212.397 us; speedup vs baseline: 1.0179x; 1.0179x over previous
//
#include <hip/hip_runtime.h>
#include <hip/hip_bf16.h>
#include <math.h>

// CodecAttention: x->QKV proj (bf16 MFMA, V written tiled-transposed, per-row
// sq-sums accumulated for RMSNorm) -> MFMA sliding-window ALiBi attention
// (win=16, norm applied in-register) -> out proj.  B=4 T=2048 DIM=1024 H=8 D=128.

#define TSEQ 2048
#define DIMW 1024
#define NHEAD 8
#define WIN 16

typedef __bf16 bf16x8_t __attribute__((ext_vector_type(8)));
typedef float f32x4_t __attribute__((ext_vector_type(4)));

__device__ __forceinline__ unsigned short f2bf(float f) {
  unsigned u = __float_as_uint(f);
  u += 0x7fffu + ((u >> 16) & 1u);   // round-to-nearest-even
  return (unsigned short)(u >> 16);
}
__device__ __forceinline__ float bflo(unsigned u) { return __uint_as_float(u << 16); }
__device__ __forceinline__ float bfhi(unsigned u) { return __uint_as_float(u & 0xffff0000u); }

// ---------- fused prep: x->bf16 | weight transpose->bf16 | zero norms ----------
__global__ __launch_bounds__(256)
void k_prep(const float* __restrict__ x, const float* __restrict__ wq,
            const float* __restrict__ wk, const float* __restrict__ wv,
            const float* __restrict__ wo, unsigned short* __restrict__ xb,
            unsigned short* __restrict__ Wt, float* __restrict__ norms) {
  const int blk = blockIdx.x;
  const int tid = threadIdx.x;
  if (blk < 8192) {                       // conv_x: 8192*256 = M*1024/4 exactly
    const int i = blk * 256 + tid;
    float4 v = ((const float4*)x)[i];
    ushort4 o;
    o.x = f2bf(v.x); o.y = f2bf(v.y); o.z = f2bf(v.z); o.w = f2bf(v.w);
    ((ushort4*)xb)[i] = o;
  } else if (blk < 12288) {               // conv_w: 4 matrices x 1024 32x32 tiles
    __shared__ float tile[32][33];
    const int zi = blk - 8192;
    const int z = zi >> 10;
    const float* src = (z == 0) ? wq : (z == 1) ? wk : (z == 2) ? wv : wo;
    const int idx = zi & 1023;
    const int n0 = (idx & 31) * 32;
    const int k0 = (idx >> 5) * 32;
    const int tx = tid & 31, ty = tid >> 5;  // 32 x 8
#pragma unroll
    for (int i = 0; i < 4; ++i)
      tile[ty + 8 * i][tx] = src[(size_t)(k0 + ty + 8 * i) * DIMW + n0 + tx];
    __syncthreads();
#pragma unroll
    for (int i = 0; i < 4; ++i)
      Wt[(size_t)z * DIMW * DIMW + (size_t)(n0 + ty + 8 * i) * DIMW + k0 + tx] =
          f2bf(tile[tx][ty + 8 * i]);
  } else {                                // zero norms[8192][2]: 32 blocks x 512
    const int i = (blk - 12288) * 512 + tid * 2;
    norms[i] = 0.f;
    norms[i + 1] = 0.f;
  }
}

// ---------- bf16 TN GEMM: 128x128 tile, ring-3, 3 blocks/CU ----------
// K-loop identical to R7 (verified: SQ_LDS_BANK_CONFLICT==0, 3 blocks/CU,
// counted vmcnt never drains to 0 until tail).  MODE 0 epilogue additionally
// accumulates per-row sum(x^2) for q (bx<8) and k (bx 8..15) into norms[row][2]
// via shfl_xor c-reduce + one f32 atomicAdd per row-frag (device-scope,
// XCD-safe) -- replaces the separate RMSNorm kernel and its 67MB round-trip.
// LDS-transpose store path (R9, aliasing-safe memcpy readback) unchanged.
#define GLDS(gp, lp)                                                        \
  __builtin_amdgcn_global_load_lds(                                         \
      (const __attribute__((address_space(1))) void*)(gp),                  \
      (__attribute__((address_space(3))) void*)(lp), 16, 0, 0)

template <int MODE>
__global__ __launch_bounds__(256, 3)
void k_gemm(const unsigned short* __restrict__ A,   // [M][K] bf16
            const unsigned short* __restrict__ Bt,  // [N][K] bf16
            unsigned short* __restrict__ Cb,        // bf16 out (MODE 0, q|k part)
            unsigned short* __restrict__ Vt,        // bf16 out (MODE 0, v part, tiled)
            float* __restrict__ Cf,                 // f32 out  (MODE 1)
            float* __restrict__ norms,              // [8192][2] sumsq (MODE 0)
            int M, int N, int K) {
  __shared__ __align__(16) unsigned char smem[49152];  // 3 x (A 8KB + B 8KB)
  const int tid = threadIdx.x;
  const int lane = tid & 63;
  const int w = tid >> 6;             // wave 0..3
  const int wm = w >> 1, wn = w & 1;  // 2 x 2

  // XCD-aware bijective swizzle (grids are multiples of 8)
  const int nwg = gridDim.x * gridDim.y;
  int flat = blockIdx.y * gridDim.x + blockIdx.x;
  flat = (flat & 7) * (nwg >> 3) + (flat >> 3);
  const int bx = flat % gridDim.x;
  const int by = flat / gridDim.x;

  // staging: per slice per thread 2 A + 2 B loads (16B each); source
  // col-group pre-swizzled: cg = (lane&3) ^ ((lane>>3)&3).
  const int r2 = lane >> 2;
  const int cg = ((lane & 3) ^ ((lane >> 3) & 3)) * 8;  // elements

#define IA(sl_, ks_, h_)                                                       \
  GLDS(A + (size_t)(by * 128 + (h_)*64 + w * 16 + r2) * K + (ks_)*32 + cg,     \
       smem + (sl_)*16384 + ((h_)*64 + w * 16) * 64)
#define IB(sl_, ks_, h_)                                                       \
  GLDS(Bt + (size_t)(bx * 128 + (h_)*64 + w * 16 + r2) * K + (ks_)*32 + cg,    \
       smem + (sl_)*16384 + 8192 + ((h_)*64 + w * 16) * 64)
#define STAGE(ks_)                                                             \
  do {                                                                         \
    const int sl_ = (ks_) % 3;                                                 \
    IA(sl_, (ks_), 0); IB(sl_, (ks_), 0);                                      \
    IA(sl_, (ks_), 1); IB(sl_, (ks_), 1);                                      \
  } while (0)

  // frag reads: slot g = (lane>>4) ^ ((lane>>1)&3)
  const int swz = ((lane >> 4) ^ ((lane >> 1) & 3)) * 16;
  const int aRd = (wm * 64 + (lane & 15)) * 64 + swz;
  const int bRd = 8192 + (wn * 64 + (lane & 15)) * 64 + swz;

  f32x4_t acc[4][4];
#pragma unroll
  for (int m = 0; m < 4; ++m)
#pragma unroll
    for (int n = 0; n < 4; ++n) acc[m][n] = (f32x4_t){0.f, 0.f, 0.f, 0.f};

  const int NS = K >> 5;  // 32 slices
  STAGE(0); STAGE(1);     // distance 2: 8 loads in flight
#pragma unroll 1
  for (int s = 0; s < NS; ++s) {
    if (s + 1 < NS) asm volatile("s_waitcnt vmcnt(4)" ::: "memory");
    else            asm volatile("s_waitcnt vmcnt(0)" ::: "memory");
    asm volatile("s_barrier" ::: "memory");
    if (s + 2 < NS) STAGE(s + 2);
    const unsigned char* sp = smem + (s % 3) * 16384;
    bf16x8_t af[4], bfr[4];
#pragma unroll
    for (int n = 0; n < 4; ++n) bfr[n] = *(const bf16x8_t*)(sp + bRd + n * 1024);
#pragma unroll
    for (int m = 0; m < 4; ++m) af[m] = *(const bf16x8_t*)(sp + aRd + m * 1024);
    __builtin_amdgcn_s_setprio(1);
#pragma unroll
    for (int m = 0; m < 4; ++m)
#pragma unroll
      for (int n = 0; n < 4; ++n)
        acc[m][n] = __builtin_amdgcn_mfma_f32_16x16x32_bf16(af[m], bfr[n], acc[m][n], 0, 0, 0);
    __builtin_amdgcn_s_setprio(0);
  }

  // ---- epilogue ----
  const int g = lane >> 4, c = lane & 15;
  if (MODE == 1) {
    // f32 out: 64B full-line runs already
    const int row0 = by * 128 + wm * 64 + (g << 2);
    const int col0 = bx * 128 + wn * 64 + c;
#pragma unroll
    for (int m = 0; m < 4; ++m)
#pragma unroll
      for (int n = 0; n < 4; ++n)
#pragma unroll
        for (int r = 0; r < 4; ++r)
          Cf[(size_t)(row0 + m * 16 + r) * N + col0 + n * 16] = acc[m][n][r];
  } else {
    const bool isV = (bx * 128 >= 2048);
    if (!isV) {
      // per-row sum(x^2) partials (16 c-lanes of same g hold one row)
      const int half = (bx < 8) ? 0 : 1;
      const int rbase = by * 128 + wm * 64 + (g << 2);
#pragma unroll
      for (int m = 0; m < 4; ++m)
#pragma unroll
        for (int r = 0; r < 4; ++r) {
          float ss = 0.f;
#pragma unroll
          for (int n = 0; n < 4; ++n) { const float v = acc[m][n][r]; ss += v * v; }
          ss += __shfl_xor(ss, 1);
          ss += __shfl_xor(ss, 2);
          ss += __shfl_xor(ss, 4);
          ss += __shfl_xor(ss, 8);
          if (c == 0) atomicAdd(norms + (size_t)(rbase + m * 16 + r) * 2 + half, ss);
        }
    }
    __syncthreads();  // staging reads done; smem reusable
    unsigned short* wbuf = (unsigned short*)(smem + w * 9216);  // [64][72]
#pragma unroll
    for (int m = 0; m < 4; ++m)
#pragma unroll
      for (int n = 0; n < 4; ++n)
#pragma unroll
        for (int r = 0; r < 4; ++r) {
          const int rl = m * 16 + (g << 2) + r;  // row (t) local 0..63
          const int cl = n * 16 + c;             // col (d) local 0..63
          const unsigned short v = f2bf(acc[m][n][r]);
          if (isV) wbuf[cl * 72 + rl] = v;       // store transposed for Vt
          else     wbuf[rl * 72 + cl] = v;
        }
    // wave-private buffer; memcpy readback is byte-typed => ordered after
    // the ushort stores (no strict-aliasing reordering).
    if (!isV) {
      const int grow = by * 128 + wm * 64;
      const int gcol = bx * 128 + wn * 64;
#pragma unroll
      for (int rr = 0; rr < 8; ++rr) {
        const int row = rr * 8 + (lane >> 3);
        const int seg = lane & 7;
        uint4 u;
        __builtin_memcpy(&u, wbuf + row * 72 + seg * 8, 16);
        *(uint4*)(Cb + (size_t)(grow + row) * 2048 + gcol + seg * 8) = u;
      }
    } else {
      const int tt0 = (by * 128 + wm * 64) & 2047;
      const int bb = (by * 128) >> 11;
      const int hh = bx - 16;
      const int dd0 = wn * 64;
      unsigned short* vdst =
          Vt + ((((size_t)(bb * NHEAD + hh)) * 256 + (tt0 >> 3)) * 128 + dd0 + lane) * 8;
#pragma unroll
      for (int tc = 0; tc < 8; ++tc) {
        uint4 u;
        __builtin_memcpy(&u, wbuf + lane * 72 + tc * 8, 16);
        *(uint4*)(vdst + (size_t)tc * 1024) = u;  // 1KB-contig t-chunk runs
      }
    }
  }
#undef IA
#undef IB
#undef STAGE
}

// ---------- MFMA sliding-window ALiBi attention (norm fused) ----------
// One wave per 16 queries of one (b,h). Key window: 32 keys [t0-16, t0+16).
// Swapped QK^T (A=K, B=Q) -> S^T. All global loads (Q, K, all 8 V-frags)
// issued BEFORE the QK^T MFMAs (T14). V read from tiled Vt2[bh][t>>3][d][t&7]
// (coalesced). RMSNorm applied in-register to Q/K frags: x * rsqrt(sum/1024
// + eps) * w[d], with row sums from the norms buffer (GEMM1-accumulated).
// Output staged per-wave in LDS [16][136], stored as 64B uint4 runs.
__device__ __forceinline__ bf16x8_t scale8(bf16x8_t v, const float* __restrict__ wp,
                                           float r) {
  bf16x8_t o;
#pragma unroll
  for (int j = 0; j < 8; ++j) {
    const float f = (float)v[j] * (r * wp[j]);
    o[j] = (__bf16)f;
  }
  return o;
}

__global__ __launch_bounds__(256)
void k_attn(const unsigned short* __restrict__ qk,   // [8192][2048] raw q|k
            const unsigned short* __restrict__ vt,   // Vt2 tiled
            const float* __restrict__ norms,         // [8192][2] sumsq
            const float* __restrict__ qnw,           // [1024]
            const float* __restrict__ knw,           // [1024]
            unsigned short* __restrict__ outb) {     // [8192][1024] bf16
  __shared__ __align__(16) unsigned char plds_all[4][1280];      // P: 16 x 80B
  __shared__ __align__(16) unsigned short obuf_all[4][16 * 136]; // out: 16 x 136
  const int lane = threadIdx.x & 63;
  const int wv = threadIdx.x >> 6;
  unsigned char* plds = plds_all[wv];
  unsigned short* obuf = obuf_all[wv];
  const int bh = blockIdx.y;                 // 0..31
  const int b = bh >> 3, h = bh & 7;
  const int t0 = blockIdx.x * 64 + wv * 16;
  const int g = lane >> 4, c = lane & 15;
  const int jlo = t0 - 16;

  // ---- issue ALL global loads first ----
  const unsigned short* qrow = qk + (size_t)(b * TSEQ + t0 + c) * 2048 + h * 128 + g * 8;
  bf16x8_t qf[4];
#pragma unroll
  for (int kc = 0; kc < 4; ++kc) qf[kc] = *(const bf16x8_t*)(qrow + kc * 32);

  const int j0 = jlo + c;
  const int j0c = (j0 < 0) ? 0 : j0;
  const unsigned short* krow0 = qk + (size_t)(b * TSEQ + j0c) * 2048 + 1024 + h * 128 + g * 8;
  const unsigned short* krow1 = qk + (size_t)(b * TSEQ + t0 + c) * 2048 + 1024 + h * 128 + g * 8;
  bf16x8_t kf0[4], kf1[4];
#pragma unroll
  for (int kc = 0; kc < 4; ++kc) {
    kf0[kc] = *(const bf16x8_t*)(krow0 + kc * 32);
    kf1[kc] = *(const bf16x8_t*)(krow1 + kc * 32);
  }

  int tc = (jlo >> 3) + g;
  if (tc < 0) tc = 0;               // masked rows: zero P weight
  const unsigned short* vbase = vt + (((size_t)bh * 256 + tc) * 128 + c) * 8;
  bf16x8_t vf[8];
#pragma unroll
  for (int n = 0; n < 8; ++n) vf[n] = *(const bf16x8_t*)(vbase + n * 128);

  // row norms (3 scalar f32 loads; L2-hot)
  const float inv1024 = 1.0f / 1024.0f;
  const float rq  = rsqrtf(norms[(size_t)(b * TSEQ + t0 + c) * 2 + 0] * inv1024 + 1e-6f);
  const float rk0 = rsqrtf(norms[(size_t)(b * TSEQ + j0c) * 2 + 1] * inv1024 + 1e-6f);
  const float rk1 = rsqrtf(norms[(size_t)(b * TSEQ + t0 + c) * 2 + 1] * inv1024 + 1e-6f);

  // ---- apply RMSNorm scales in-register ----
#pragma unroll
  for (int kc = 0; kc < 4; ++kc) {
    const float* qwp = qnw + h * 128 + kc * 32 + g * 8;
    const float* kwp = knw + h * 128 + kc * 32 + g * 8;
    qf[kc] = scale8(qf[kc], qwp, rq);
    kf0[kc] = scale8(kf0[kc], kwp, rk0);
    kf1[kc] = scale8(kf1[kc], kwp, rk1);
  }

  // ---- QK^T ----
  f32x4_t s0 = (f32x4_t){0.f, 0.f, 0.f, 0.f};
  f32x4_t s1 = (f32x4_t){0.f, 0.f, 0.f, 0.f};
#pragma unroll
  for (int kc = 0; kc < 4; ++kc) {
    s0 = __builtin_amdgcn_mfma_f32_16x16x32_bf16(kf0[kc], qf[kc], s0, 0, 0, 0);
    s1 = __builtin_amdgcn_mfma_f32_16x16x32_bf16(kf1[kc], qf[kc], s1, 0, 0, 0);
  }

  // scores + mask + bias. key kk = z*16 + g*4 + r; query = c; rel = kk-16-c.
  const float scale = 0.08838834764831845f;  // 1/sqrt(128)
  const float slope = 1.0f / (float)(1 << h);
  float val[8];
#pragma unroll
  for (int z = 0; z < 2; ++z)
#pragma unroll
    for (int r = 0; r < 4; ++r) {
      const int kk = z * 16 + g * 4 + r;
      const int rel = kk - 16 - c;
      const bool ok = (rel <= 0) & (rel >= -WIN) & (jlo + kk >= 0);
      const float sc = (z == 0) ? s0[r] : s1[r];
      val[z * 4 + r] = ok ? (sc * scale + slope * (float)rel) : -1.0e30f;
    }
  float m = val[0];
#pragma unroll
  for (int i = 1; i < 8; ++i) m = fmaxf(m, val[i]);
  m = fmaxf(m, __shfl_xor(m, 16));
  m = fmaxf(m, __shfl_xor(m, 32));
  float e[8], s = 0.f;
#pragma unroll
  for (int i = 0; i < 8; ++i) { e[i] = __expf(val[i] - m); s += e[i]; }
  s += __shfl_xor(s, 16);
  s += __shfl_xor(s, 32);
  const float inv = 1.0f / s;

  // P -> LDS [query c][key kk], row stride 80B: 2-way banks = free
#pragma unroll
  for (int z = 0; z < 2; ++z) {
    uint2 pk;
    pk.x = (unsigned)f2bf(e[z * 4 + 0] * inv) | ((unsigned)f2bf(e[z * 4 + 1] * inv) << 16);
    pk.y = (unsigned)f2bf(e[z * 4 + 2] * inv) | ((unsigned)f2bf(e[z * 4 + 3] * inv) << 16);
    *(uint2*)(plds + c * 80 + z * 32 + g * 8) = pk;
  }
  const bf16x8_t pf = *(const bf16x8_t*)(plds + c * 80 + g * 16);

  // ---- PV -> LDS out-tile ----
#pragma unroll
  for (int n = 0; n < 8; ++n) {
    f32x4_t o = __builtin_amdgcn_mfma_f32_16x16x32_bf16(pf, vf[n], (f32x4_t){0.f, 0.f, 0.f, 0.f},
                                                        0, 0, 0);
#pragma unroll
    for (int r = 0; r < 4; ++r)
      obuf[(g * 4 + r) * 136 + n * 16 + c] = f2bf(o[r]);
  }

  // ---- coalesced store: 4 uint4 per lane, 64B runs ----
  unsigned short* obase = outb + (size_t)(b * TSEQ + t0) * 1024 + h * 128;
  const int q = lane >> 2, s4 = lane & 3;
#pragma unroll
  for (int i = 0; i < 4; ++i) {
    const int seg = i * 4 + s4;
    uint4 u;
    __builtin_memcpy(&u, obuf + q * 136 + seg * 8, 16);
    *(uint4*)(obase + (size_t)q * 1024 + seg * 8) = u;
  }
}

extern "C" void kernel_launch(void* const* d_in, const int* in_sizes, int n_in,
                              void* d_out, int out_size, void* d_ws, size_t ws_size,
                              hipStream_t stream) {
  const float* x = (const float*)d_in[0];
  const float* wq = (const float*)d_in[1];
  const float* wk = (const float*)d_in[2];
  const float* wv = (const float*)d_in[3];
  const float* wo = (const float*)d_in[4];
  const float* qnw = (const float*)d_in[5];
  const float* knw = (const float*)d_in[6];
  float* out = (float*)d_out;

  const int M = 4 * TSEQ;  // 8192 rows
  // workspace (75.6 MB):
  //   xb    [M][1024] bf16 (16.8 MB) -- x bf16; later reused as attention output
  //   Wt    [4][1024][1024] bf16 (8.4 MB)
  //   qk    [M][2048] bf16 (33.5 MB) -- raw q|k (norm applied in attn)
  //   Vt2   [32][256][128][8] bf16 (16.8 MB) -- V tiled-transposed per (b,h)
  //   norms [M][2] f32 (64 KB) -- per-row sum(x^2) for q,k
  unsigned short* xb = (unsigned short*)d_ws;
  unsigned short* Wt = xb + (size_t)M * DIMW;
  unsigned short* qkb = Wt + (size_t)4 * DIMW * DIMW;
  unsigned short* Vt = qkb + (size_t)M * 2048;
  float* norms = (float*)(Vt + (size_t)M * 1024);
  if (ws_size < ((size_t)M * DIMW + (size_t)4 * DIMW * DIMW + (size_t)M * 2048 +
                 (size_t)M * 1024) * 2 + (size_t)M * 2 * 4) return;

  k_prep<<<12320, 256, 0, stream>>>(x, wq, wk, wv, wo, xb, Wt, norms);
  k_gemm<0><<<dim3(24, 64), 256, 0, stream>>>(xb, Wt, qkb, Vt, nullptr, norms, M, 3072, 1024);
  k_attn<<<dim3(TSEQ / 64, 32), 256, 0, stream>>>(qkb, Vt, norms, qnw, knw, xb);
  k_gemm<1><<<dim3(8, 64), 256, 0, stream>>>(xb, Wt + (size_t)3 * DIMW * DIMW, nullptr,
                                             nullptr, out, nullptr, M, 1024, 1024);
}

// Round 11
// 206.249 us; speedup vs baseline: 1.0483x; 1.0298x over previous
//
#include <hip/hip_runtime.h>
#include <hip/hip_bf16.h>
#include <math.h>

// CodecAttention: x->QKV proj (bf16 MFMA, V written tiled-transposed) ->
// k_norms (per-row sumsq) -> MFMA sliding-window ALiBi attention (win=16,
// RMSNorm applied in-register) -> out proj.  B=4 T=2048 DIM=1024 H=8 D=128.

#define TSEQ 2048
#define DIMW 1024
#define NHEAD 8
#define WIN 16

typedef __bf16 bf16x8_t __attribute__((ext_vector_type(8)));
typedef float f32x4_t __attribute__((ext_vector_type(4)));

__device__ __forceinline__ unsigned short f2bf(float f) {
  unsigned u = __float_as_uint(f);
  u += 0x7fffu + ((u >> 16) & 1u);   // round-to-nearest-even
  return (unsigned short)(u >> 16);
}
__device__ __forceinline__ float bflo(unsigned u) { return __uint_as_float(u << 16); }
__device__ __forceinline__ float bfhi(unsigned u) { return __uint_as_float(u & 0xffff0000u); }

// ---------- fused prep: x->bf16 | weight transpose->bf16 ----------
__global__ __launch_bounds__(256)
void k_prep(const float* __restrict__ x, const float* __restrict__ wq,
            const float* __restrict__ wk, const float* __restrict__ wv,
            const float* __restrict__ wo, unsigned short* __restrict__ xb,
            unsigned short* __restrict__ Wt) {
  const int blk = blockIdx.x;
  const int tid = threadIdx.x;
  if (blk < 8192) {                       // conv_x: 8192*256 = M*1024/4 exactly
    const int i = blk * 256 + tid;
    float4 v = ((const float4*)x)[i];
    ushort4 o;
    o.x = f2bf(v.x); o.y = f2bf(v.y); o.z = f2bf(v.z); o.w = f2bf(v.w);
    ((ushort4*)xb)[i] = o;
  } else {                                // conv_w: 4 matrices x 1024 32x32 tiles
    __shared__ float tile[32][33];
    const int zi = blk - 8192;
    const int z = zi >> 10;
    const float* src = (z == 0) ? wq : (z == 1) ? wk : (z == 2) ? wv : wo;
    const int idx = zi & 1023;
    const int n0 = (idx & 31) * 32;
    const int k0 = (idx >> 5) * 32;
    const int tx = tid & 31, ty = tid >> 5;  // 32 x 8
#pragma unroll
    for (int i = 0; i < 4; ++i)
      tile[ty + 8 * i][tx] = src[(size_t)(k0 + ty + 8 * i) * DIMW + n0 + tx];
    __syncthreads();
#pragma unroll
    for (int i = 0; i < 4; ++i)
      Wt[(size_t)z * DIMW * DIMW + (size_t)(n0 + ty + 8 * i) * DIMW + k0 + tx] =
          f2bf(tile[tx][ty + 8 * i]);
  }
}

// ---------- bf16 TN GEMM: 128x128 tile, ring-3, 3 blocks/CU ----------
// K-loop identical to R7 (verified: SQ_LDS_BANK_CONFLICT==0 in-loop, 3
// blocks/CU, counted vmcnt never drains to 0 until tail).  Epilogue = R9
// LDS-transpose store path (aliasing-safe memcpy readback).  R11: the R10
// atomic norm-accumulation is REVERTED -- it cost GEMM1 +14.8us (WRITE_SIZE
// +8MB write-allocate + LLC serialization of 131K cross-XCD atomics);
// sumsq now computed by the standalone k_norms pass (6us).
#define GLDS(gp, lp)                                                        \
  __builtin_amdgcn_global_load_lds(                                         \
      (const __attribute__((address_space(1))) void*)(gp),                  \
      (__attribute__((address_space(3))) void*)(lp), 16, 0, 0)

template <int MODE>
__global__ __launch_bounds__(256, 3)
void k_gemm(const unsigned short* __restrict__ A,   // [M][K] bf16
            const unsigned short* __restrict__ Bt,  // [N][K] bf16
            unsigned short* __restrict__ Cb,        // bf16 out (MODE 0, q|k part)
            unsigned short* __restrict__ Vt,        // bf16 out (MODE 0, v part, tiled)
            float* __restrict__ Cf,                 // f32 out  (MODE 1)
            int M, int N, int K) {
  __shared__ __align__(16) unsigned char smem[49152];  // 3 x (A 8KB + B 8KB)
  const int tid = threadIdx.x;
  const int lane = tid & 63;
  const int w = tid >> 6;             // wave 0..3
  const int wm = w >> 1, wn = w & 1;  // 2 x 2

  // XCD-aware bijective swizzle (grids are multiples of 8)
  const int nwg = gridDim.x * gridDim.y;
  int flat = blockIdx.y * gridDim.x + blockIdx.x;
  flat = (flat & 7) * (nwg >> 3) + (flat >> 3);
  const int bx = flat % gridDim.x;
  const int by = flat / gridDim.x;

  // staging: per slice per thread 2 A + 2 B loads (16B each); source
  // col-group pre-swizzled: cg = (lane&3) ^ ((lane>>3)&3).
  const int r2 = lane >> 2;
  const int cg = ((lane & 3) ^ ((lane >> 3) & 3)) * 8;  // elements

#define IA(sl_, ks_, h_)                                                       \
  GLDS(A + (size_t)(by * 128 + (h_)*64 + w * 16 + r2) * K + (ks_)*32 + cg,     \
       smem + (sl_)*16384 + ((h_)*64 + w * 16) * 64)
#define IB(sl_, ks_, h_)                                                       \
  GLDS(Bt + (size_t)(bx * 128 + (h_)*64 + w * 16 + r2) * K + (ks_)*32 + cg,    \
       smem + (sl_)*16384 + 8192 + ((h_)*64 + w * 16) * 64)
#define STAGE(ks_)                                                             \
  do {                                                                         \
    const int sl_ = (ks_) % 3;                                                 \
    IA(sl_, (ks_), 0); IB(sl_, (ks_), 0);                                      \
    IA(sl_, (ks_), 1); IB(sl_, (ks_), 1);                                      \
  } while (0)

  // frag reads: slot g = (lane>>4) ^ ((lane>>1)&3)
  const int swz = ((lane >> 4) ^ ((lane >> 1) & 3)) * 16;
  const int aRd = (wm * 64 + (lane & 15)) * 64 + swz;
  const int bRd = 8192 + (wn * 64 + (lane & 15)) * 64 + swz;

  f32x4_t acc[4][4];
#pragma unroll
  for (int m = 0; m < 4; ++m)
#pragma unroll
    for (int n = 0; n < 4; ++n) acc[m][n] = (f32x4_t){0.f, 0.f, 0.f, 0.f};

  const int NS = K >> 5;  // 32 slices
  STAGE(0); STAGE(1);     // distance 2: 8 loads in flight
#pragma unroll 1
  for (int s = 0; s < NS; ++s) {
    if (s + 1 < NS) asm volatile("s_waitcnt vmcnt(4)" ::: "memory");
    else            asm volatile("s_waitcnt vmcnt(0)" ::: "memory");
    asm volatile("s_barrier" ::: "memory");
    if (s + 2 < NS) STAGE(s + 2);
    const unsigned char* sp = smem + (s % 3) * 16384;
    bf16x8_t af[4], bfr[4];
#pragma unroll
    for (int n = 0; n < 4; ++n) bfr[n] = *(const bf16x8_t*)(sp + bRd + n * 1024);
#pragma unroll
    for (int m = 0; m < 4; ++m) af[m] = *(const bf16x8_t*)(sp + aRd + m * 1024);
    __builtin_amdgcn_s_setprio(1);
#pragma unroll
    for (int m = 0; m < 4; ++m)
#pragma unroll
      for (int n = 0; n < 4; ++n)
        acc[m][n] = __builtin_amdgcn_mfma_f32_16x16x32_bf16(af[m], bfr[n], acc[m][n], 0, 0, 0);
    __builtin_amdgcn_s_setprio(0);
  }

  // ---- epilogue ----
  const int g = lane >> 4, c = lane & 15;
  if (MODE == 1) {
    // f32 out: 64B full-line runs already
    const int row0 = by * 128 + wm * 64 + (g << 2);
    const int col0 = bx * 128 + wn * 64 + c;
#pragma unroll
    for (int m = 0; m < 4; ++m)
#pragma unroll
      for (int n = 0; n < 4; ++n)
#pragma unroll
        for (int r = 0; r < 4; ++r)
          Cf[(size_t)(row0 + m * 16 + r) * N + col0 + n * 16] = acc[m][n][r];
  } else {
    __syncthreads();  // staging reads done; smem reusable
    unsigned short* wbuf = (unsigned short*)(smem + w * 9216);  // [64][72]
    const bool isV = (bx * 128 >= 2048);
#pragma unroll
    for (int m = 0; m < 4; ++m)
#pragma unroll
      for (int n = 0; n < 4; ++n)
#pragma unroll
        for (int r = 0; r < 4; ++r) {
          const int rl = m * 16 + (g << 2) + r;  // row (t) local 0..63
          const int cl = n * 16 + c;             // col (d) local 0..63
          const unsigned short v = f2bf(acc[m][n][r]);
          if (isV) wbuf[cl * 72 + rl] = v;       // store transposed for Vt
          else     wbuf[rl * 72 + cl] = v;
        }
    // wave-private buffer; memcpy readback is byte-typed => ordered after
    // the ushort stores (no strict-aliasing reordering).
    if (!isV) {
      const int grow = by * 128 + wm * 64;
      const int gcol = bx * 128 + wn * 64;
#pragma unroll
      for (int rr = 0; rr < 8; ++rr) {
        const int row = rr * 8 + (lane >> 3);
        const int seg = lane & 7;
        uint4 u;
        __builtin_memcpy(&u, wbuf + row * 72 + seg * 8, 16);
        *(uint4*)(Cb + (size_t)(grow + row) * 2048 + gcol + seg * 8) = u;
      }
    } else {
      const int tt0 = (by * 128 + wm * 64) & 2047;
      const int bb = (by * 128) >> 11;
      const int hh = bx - 16;
      const int dd0 = wn * 64;
      unsigned short* vdst =
          Vt + ((((size_t)(bb * NHEAD + hh)) * 256 + (tt0 >> 3)) * 128 + dd0 + lane) * 8;
#pragma unroll
      for (int tc = 0; tc < 8; ++tc) {
        uint4 u;
        __builtin_memcpy(&u, wbuf + lane * 72 + tc * 8, 16);
        *(uint4*)(vdst + (size_t)tc * 1024) = u;  // 1KB-contig t-chunk runs
      }
    }
  }
#undef IA
#undef IB
#undef STAGE
}

// ---------- per-row sumsq for RMSNorm: norms[row] = {sum q^2, sum k^2} ----------
// One wave per row: 4x uint4/lane coalesced (4KB row), lanes 0..31 cover the
// q half, 32..63 the k half; 5-step shfl reduce within each 32-lane group.
// 33.5MB read + 64KB write ~ 6us (replaces R10's GEMM1-epilogue atomics,
// which cost +14.8us of LLC-serialized write-allocate).
__global__ __launch_bounds__(256)
void k_norms(const unsigned short* __restrict__ qk, float* __restrict__ norms) {
  const int row = blockIdx.x * 4 + (threadIdx.x >> 6);
  const int lane = threadIdx.x & 63;
  const unsigned short* p = qk + (size_t)row * 2048 + lane * 32;
  float ss = 0.f;
#pragma unroll
  for (int i = 0; i < 4; ++i) {
    uint4 u;
    __builtin_memcpy(&u, p + i * 8, 16);
    ss += bflo(u.x) * bflo(u.x) + bfhi(u.x) * bfhi(u.x);
    ss += bflo(u.y) * bflo(u.y) + bfhi(u.y) * bfhi(u.y);
    ss += bflo(u.z) * bflo(u.z) + bfhi(u.z) * bfhi(u.z);
    ss += bflo(u.w) * bflo(u.w) + bfhi(u.w) * bfhi(u.w);
  }
#pragma unroll
  for (int off = 16; off > 0; off >>= 1) ss += __shfl_xor(ss, off);
  if ((lane & 31) == 0) norms[(size_t)row * 2 + (lane >> 5)] = ss;
}

// ---------- MFMA sliding-window ALiBi attention (norm applied in-register) ----------
// One wave per 16 queries of one (b,h). Key window: 32 keys [t0-16, t0+16).
// Swapped QK^T (A=K, B=Q) -> S^T. All global loads (Q, K, all 8 V-frags)
// issued BEFORE the QK^T MFMAs (T14). V read from tiled Vt2[bh][t>>3][d][t&7]
// (coalesced). RMSNorm applied in-register to Q/K frags: x * rsqrt(sum/1024
// + eps) * w[d], with row sums from the norms buffer (k_norms-computed).
// Output staged per-wave in LDS [16][136], stored as 64B uint4 runs.
__device__ __forceinline__ bf16x8_t scale8(bf16x8_t v, const float* __restrict__ wp,
                                           float r) {
  bf16x8_t o;
#pragma unroll
  for (int j = 0; j < 8; ++j) {
    const float f = (float)v[j] * (r * wp[j]);
    o[j] = (__bf16)f;
  }
  return o;
}

__global__ __launch_bounds__(256)
void k_attn(const unsigned short* __restrict__ qk,   // [8192][2048] raw q|k
            const unsigned short* __restrict__ vt,   // Vt2 tiled
            const float* __restrict__ norms,         // [8192][2] sumsq
            const float* __restrict__ qnw,           // [1024]
            const float* __restrict__ knw,           // [1024]
            unsigned short* __restrict__ outb) {     // [8192][1024] bf16
  __shared__ __align__(16) unsigned char plds_all[4][1280];      // P: 16 x 80B
  __shared__ __align__(16) unsigned short obuf_all[4][16 * 136]; // out: 16 x 136
  const int lane = threadIdx.x & 63;
  const int wv = threadIdx.x >> 6;
  unsigned char* plds = plds_all[wv];
  unsigned short* obuf = obuf_all[wv];
  const int bh = blockIdx.y;                 // 0..31
  const int b = bh >> 3, h = bh & 7;
  const int t0 = blockIdx.x * 64 + wv * 16;
  const int g = lane >> 4, c = lane & 15;
  const int jlo = t0 - 16;

  // ---- issue ALL global loads first ----
  const unsigned short* qrow = qk + (size_t)(b * TSEQ + t0 + c) * 2048 + h * 128 + g * 8;
  bf16x8_t qf[4];
#pragma unroll
  for (int kc = 0; kc < 4; ++kc) qf[kc] = *(const bf16x8_t*)(qrow + kc * 32);

  const int j0 = jlo + c;
  const int j0c = (j0 < 0) ? 0 : j0;
  const unsigned short* krow0 = qk + (size_t)(b * TSEQ + j0c) * 2048 + 1024 + h * 128 + g * 8;
  const unsigned short* krow1 = qk + (size_t)(b * TSEQ + t0 + c) * 2048 + 1024 + h * 128 + g * 8;
  bf16x8_t kf0[4], kf1[4];
#pragma unroll
  for (int kc = 0; kc < 4; ++kc) {
    kf0[kc] = *(const bf16x8_t*)(krow0 + kc * 32);
    kf1[kc] = *(const bf16x8_t*)(krow1 + kc * 32);
  }

  int tc = (jlo >> 3) + g;
  if (tc < 0) tc = 0;               // masked rows: zero P weight
  const unsigned short* vbase = vt + (((size_t)bh * 256 + tc) * 128 + c) * 8;
  bf16x8_t vf[8];
#pragma unroll
  for (int n = 0; n < 8; ++n) vf[n] = *(const bf16x8_t*)(vbase + n * 128);

  // row norms (3 scalar f32 loads; L2-hot)
  const float inv1024 = 1.0f / 1024.0f;
  const float rq  = rsqrtf(norms[(size_t)(b * TSEQ + t0 + c) * 2 + 0] * inv1024 + 1e-6f);
  const float rk0 = rsqrtf(norms[(size_t)(b * TSEQ + j0c) * 2 + 1] * inv1024 + 1e-6f);
  const float rk1 = rsqrtf(norms[(size_t)(b * TSEQ + t0 + c) * 2 + 1] * inv1024 + 1e-6f);

  // ---- apply RMSNorm scales in-register ----
#pragma unroll
  for (int kc = 0; kc < 4; ++kc) {
    const float* qwp = qnw + h * 128 + kc * 32 + g * 8;
    const float* kwp = knw + h * 128 + kc * 32 + g * 8;
    qf[kc] = scale8(qf[kc], qwp, rq);
    kf0[kc] = scale8(kf0[kc], kwp, rk0);
    kf1[kc] = scale8(kf1[kc], kwp, rk1);
  }

  // ---- QK^T ----
  f32x4_t s0 = (f32x4_t){0.f, 0.f, 0.f, 0.f};
  f32x4_t s1 = (f32x4_t){0.f, 0.f, 0.f, 0.f};
#pragma unroll
  for (int kc = 0; kc < 4; ++kc) {
    s0 = __builtin_amdgcn_mfma_f32_16x16x32_bf16(kf0[kc], qf[kc], s0, 0, 0, 0);
    s1 = __builtin_amdgcn_mfma_f32_16x16x32_bf16(kf1[kc], qf[kc], s1, 0, 0, 0);
  }

  // scores + mask + bias. key kk = z*16 + g*4 + r; query = c; rel = kk-16-c.
  const float scale = 0.08838834764831845f;  // 1/sqrt(128)
  const float slope = 1.0f / (float)(1 << h);
  float val[8];
#pragma unroll
  for (int z = 0; z < 2; ++z)
#pragma unroll
    for (int r = 0; r < 4; ++r) {
      const int kk = z * 16 + g * 4 + r;
      const int rel = kk - 16 - c;
      const bool ok = (rel <= 0) & (rel >= -WIN) & (jlo + kk >= 0);
      const float sc = (z == 0) ? s0[r] : s1[r];
      val[z * 4 + r] = ok ? (sc * scale + slope * (float)rel) : -1.0e30f;
    }
  float m = val[0];
#pragma unroll
  for (int i = 1; i < 8; ++i) m = fmaxf(m, val[i]);
  m = fmaxf(m, __shfl_xor(m, 16));
  m = fmaxf(m, __shfl_xor(m, 32));
  float e[8], s = 0.f;
#pragma unroll
  for (int i = 0; i < 8; ++i) { e[i] = __expf(val[i] - m); s += e[i]; }
  s += __shfl_xor(s, 16);
  s += __shfl_xor(s, 32);
  const float inv = 1.0f / s;

  // P -> LDS [query c][key kk], row stride 80B: 2-way banks = free
#pragma unroll
  for (int z = 0; z < 2; ++z) {
    uint2 pk;
    pk.x = (unsigned)f2bf(e[z * 4 + 0] * inv) | ((unsigned)f2bf(e[z * 4 + 1] * inv) << 16);
    pk.y = (unsigned)f2bf(e[z * 4 + 2] * inv) | ((unsigned)f2bf(e[z * 4 + 3] * inv) << 16);
    *(uint2*)(plds + c * 80 + z * 32 + g * 8) = pk;
  }
  const bf16x8_t pf = *(const bf16x8_t*)(plds + c * 80 + g * 16);

  // ---- PV -> LDS out-tile ----
#pragma unroll
  for (int n = 0; n < 8; ++n) {
    f32x4_t o = __builtin_amdgcn_mfma_f32_16x16x32_bf16(pf, vf[n], (f32x4_t){0.f, 0.f, 0.f, 0.f},
                                                        0, 0, 0);
#pragma unroll
    for (int r = 0; r < 4; ++r)
      obuf[(g * 4 + r) * 136 + n * 16 + c] = f2bf(o[r]);
  }

  // ---- coalesced store: 4 uint4 per lane, 64B runs ----
  unsigned short* obase = outb + (size_t)(b * TSEQ + t0) * 1024 + h * 128;
  const int q = lane >> 2, s4 = lane & 3;
#pragma unroll
  for (int i = 0; i < 4; ++i) {
    const int seg = i * 4 + s4;
    uint4 u;
    __builtin_memcpy(&u, obuf + q * 136 + seg * 8, 16);
    *(uint4*)(obase + (size_t)q * 1024 + seg * 8) = u;
  }
}

extern "C" void kernel_launch(void* const* d_in, const int* in_sizes, int n_in,
                              void* d_out, int out_size, void* d_ws, size_t ws_size,
                              hipStream_t stream) {
  const float* x = (const float*)d_in[0];
  const float* wq = (const float*)d_in[1];
  const float* wk = (const float*)d_in[2];
  const float* wv = (const float*)d_in[3];
  const float* wo = (const float*)d_in[4];
  const float* qnw = (const float*)d_in[5];
  const float* knw = (const float*)d_in[6];
  float* out = (float*)d_out;

  const int M = 4 * TSEQ;  // 8192 rows
  // workspace (75.6 MB):
  //   xb    [M][1024] bf16 (16.8 MB) -- x bf16; later reused as attention output
  //   Wt    [4][1024][1024] bf16 (8.4 MB)
  //   qk    [M][2048] bf16 (33.5 MB) -- raw q|k (norm applied in attn)
  //   Vt2   [32][256][128][8] bf16 (16.8 MB) -- V tiled-transposed per (b,h)
  //   norms [M][2] f32 (64 KB) -- per-row sum(x^2) for q,k
  unsigned short* xb = (unsigned short*)d_ws;
  unsigned short* Wt = xb + (size_t)M * DIMW;
  unsigned short* qkb = Wt + (size_t)4 * DIMW * DIMW;
  unsigned short* Vt = qkb + (size_t)M * 2048;
  float* norms = (float*)(Vt + (size_t)M * 1024);
  if (ws_size < ((size_t)M * DIMW + (size_t)4 * DIMW * DIMW + (size_t)M * 2048 +
                 (size_t)M * 1024) * 2 + (size_t)M * 2 * 4) return;

  k_prep<<<12288, 256, 0, stream>>>(x, wq, wk, wv, wo, xb, Wt);
  k_gemm<0><<<dim3(24, 64), 256, 0, stream>>>(xb, Wt, qkb, Vt, nullptr, M, 3072, 1024);
  k_norms<<<M / 4, 256, 0, stream>>>(qkb, norms);
  k_attn<<<dim3(TSEQ / 64, 32), 256, 0, stream>>>(qkb, Vt, norms, qnw, knw, xb);
  k_gemm<1><<<dim3(8, 64), 256, 0, stream>>>(xb, Wt + (size_t)3 * DIMW * DIMW, nullptr,
                                             nullptr, out, M, 1024, 1024);
}